// Round 3
// baseline (285.548 us; speedup 1.0000x reference)
//
#include <hip/hip_runtime.h>

#define TBL 4096

// ---- ws float-layout ----
#define WS_SPB 0      // 64 f32 : s[d] + pos_b2[d]
#define WS_C0  64     // 8 f32  : attn_b1[h] + sum_d pos_b2[d]*w1[d][h]
#define WS_IMG 128    // bf16 lane-images, 29 images x 64 lanes x 16B (256 f32 slots each)
// image indices
#define IMG_BH  0     // 4 chunks: 0,1 = At (k path); 2,3 = -Bqt (q path)
#define IMG_BCT 4     // 1
#define IMG_BP  5     // 4 (t): pos_w2 B-frag
#define IMG_BW2 9     // 4 (t): attn_w2 B-frag
#define IMG_BV  13    // 8 (t*2+c): Wv B-frag
#define IMG_BO  21    // 8 (t*2+c): out_w B-frag
// total ws = 128 + 29*256 = 7552 floats = 30208 bytes

typedef __attribute__((ext_vector_type(8))) short bf16x8;
typedef __attribute__((ext_vector_type(4))) float f32x4;

__device__ inline int cvt2bf(float a, float b) {
    int r;
    asm("v_cvt_pk_bf16_f32 %0, %1, %2" : "=v"(r) : "v"(a), "v"(b));
    return r;
}

__device__ inline bf16x8 pack8(const float* x) {
    union { int4 i; bf16x8 b; } u;
    u.i.x = cvt2bf(x[0], x[1]);
    u.i.y = cvt2bf(x[2], x[3]);
    u.i.z = cvt2bf(x[4], x[5]);
    u.i.w = cvt2bf(x[6], x[7]);
    return u.b;
}

__device__ inline bf16x8 pack2f4(float4 a, float4 b) {
    float t[8] = {a.x, a.y, a.z, a.w, b.x, b.y, b.z, b.w};
    return pack8(t);
}

__device__ inline bf16x8 loadpack(const float* p) {
    float4 a = *(const float4*)p;
    float4 b = *(const float4*)(p + 4);
    return pack2f4(a, b);
}

// lane <-> lane^16 exchange (q4 pair swap), BitMode xor=16
__device__ inline float swz16(float x) {
    return __int_as_float(__builtin_amdgcn_ds_swizzle(__float_as_int(x), 0x401F));
}

// Latency-optimized precompute: 30 blocks x 256 threads. Every reduction loop
// is fully unrolled with the d-dimension split across 4 thread-groups (LDS
// tree reduce) so cold HBM loads overlap instead of serializing.
__global__ __launch_bounds__(256) void precompute_kernel(
    const float* __restrict__ strength, const float* __restrict__ str_w,
    const float* __restrict__ str_b,
    const float* __restrict__ q_tbl, const float* __restrict__ k_tbl,
    const float* __restrict__ v_tbl, const float* __restrict__ out_w,
    const float* __restrict__ attn_w1, const float* __restrict__ attn_b1,
    const float* __restrict__ attn_w2,
    const float* __restrict__ pos_w2, const float* __restrict__ pos_b2,
    const int* __restrict__ embed_id, float* __restrict__ ws)
{
    __shared__ float red[4][64];        // block 0: s partials
    __shared__ float red2[4][64][8];    // image blocks: 4-way d partials

    const int t    = threadIdx.x;
    const int b    = blockIdx.x;
    const int id   = embed_id[0];
    const int lane = t & 63;
    const int dp   = t >> 6;            // d-partition / thread-group 0..3
    const int q4   = lane >> 4;
    const int col  = lane & 15;

    if (b == 0) {
        // s[d] = strength . str_w[:,d] ; 4 partitions x 128 i, 4 accumulators.
        {
            const float* st = strength + dp * 128;
            const float* sw = str_w + (size_t)(dp * 128) * 64 + lane;
            float a0 = 0.f, a1 = 0.f, a2 = 0.f, a3 = 0.f;
            #pragma unroll
            for (int i = 0; i < 128; i += 4) {
                a0 += st[i]     * sw[(size_t)(i)     * 64];
                a1 += st[i + 1] * sw[(size_t)(i + 1) * 64];
                a2 += st[i + 2] * sw[(size_t)(i + 2) * 64];
                a3 += st[i + 3] * sw[(size_t)(i + 3) * 64];
            }
            red[dp][lane] = (a0 + a1) + (a2 + a3);
        }
        // C0[h] = attn_b1[h] + pos_b2 . attn_w1[:,h]  (fully unrolled, tiny)
        if (t < 8) {
            float c = attn_b1[t];
            #pragma unroll
            for (int d = 0; d < 64; ++d) c += pos_b2[d] * attn_w1[d * 8 + t];
            ws[WS_C0 + t] = c;
        }
        __syncthreads();
        if (t < 64)
            ws[WS_SPB + t] = red[0][t] + red[1][t] + red[2][t] + red[3][t]
                           + str_b[t] + pos_b2[t];
        return;
    }

    const int im = b - 1;               // 0..28

    if (im < 5) {
        // dot-product images: split the 64-term d-reduction across dp groups
        float val[8];
        #pragma unroll
        for (int j = 0; j < 8; ++j) val[j] = 0.f;

        if (im < 4) {                   // HID chunks: B[k][n=col<8]
            const float* tbl = (im < 2 ? k_tbl : q_tbl) + (size_t)id * TBL;
            const int kb = (im & 1) * 32 + q4 * 8;
            if (col < 8) {
                #pragma unroll
                for (int dd = 0; dd < 16; ++dd) {
                    const int d = dp * 16 + dd;
                    const float w = attn_w1[d * 8 + col];
                    const float4 t0 = *(const float4*)(tbl + d * 64 + kb);
                    const float4 t1 = *(const float4*)(tbl + d * 64 + kb + 4);
                    val[0] += t0.x * w; val[1] += t0.y * w;
                    val[2] += t0.z * w; val[3] += t0.w * w;
                    val[4] += t1.x * w; val[5] += t1.y * w;
                    val[6] += t1.z * w; val[7] += t1.w * w;
                }
            }
        } else {                        // Ct: B[k=g (q4==0)][n=col<8]
            if (q4 == 0 && col < 8) {
                #pragma unroll
                for (int dd = 0; dd < 16; ++dd) {
                    const int d = dp * 16 + dd;
                    const float w = attn_w1[d * 8 + col];
                    #pragma unroll
                    for (int j = 0; j < 8; ++j) val[j] += pos_w2[j * 64 + d] * w;
                }
            }
        }
        #pragma unroll
        for (int j = 0; j < 8; ++j) red2[dp][lane][j] = val[j];
        __syncthreads();
        if (dp == 0) {
            const float sgn = (im == 2 || im == 3) ? -1.f : 1.f;
            float v2[8];
            #pragma unroll
            for (int j = 0; j < 8; ++j)
                v2[j] = sgn * (red2[0][lane][j] + red2[1][lane][j] +
                               red2[2][lane][j] + red2[3][lane][j]);
            ((bf16x8*)(ws + WS_IMG))[im * 64 + lane] = pack8(v2);
        }
        return;
    }

    // copy/reformat images: one thread-group, fully unrolled loads
    if (dp == 0) {
        float val[8];
        #pragma unroll
        for (int j = 0; j < 8; ++j) val[j] = 0.f;

        if (im < 9) {                   // Bp[t]: B[k=g (q4==0)][n=d]
            const int tt = im - 5;
            if (q4 == 0) {
                #pragma unroll
                for (int j = 0; j < 8; ++j) val[j] = pos_w2[j * 64 + tt * 16 + col];
            }
        } else if (im < 13) {           // Bw2[t]: B[k=h (q4==0)][n=d]
            const int tt = im - 9;
            if (q4 == 0) {
                #pragma unroll
                for (int j = 0; j < 8; ++j) val[j] = attn_w2[j * 64 + tt * 16 + col];
            }
        } else if (im < 21) {           // Bv[t][c]: B[k=j][n=d] = Wv[n][k]
            const int e = im - 13, tt = e >> 1, c = e & 1;
            const float* p = v_tbl + (size_t)id * TBL +
                             (tt * 16 + col) * 64 + c * 32 + q4 * 8;
            const float4 t0 = *(const float4*)p;
            const float4 t1 = *(const float4*)(p + 4);
            val[0] = t0.x; val[1] = t0.y; val[2] = t0.z; val[3] = t0.w;
            val[4] = t1.x; val[5] = t1.y; val[6] = t1.z; val[7] = t1.w;
        } else {                        // Bo[t][c]: B[k=d][n=e] = out_w[d][e]
            const int e = im - 21, tt = e >> 1, c = e & 1;
            #pragma unroll
            for (int j = 0; j < 8; ++j)
                val[j] = out_w[(c * 32 + q4 * 8 + j) * 64 + tt * 16 + col];
        }
        ((bf16x8*)(ws + WS_IMG))[im * 64 + lane] = pack8(val);
    }
}

// One wave handles 8 bn (4 pairs of 2). All LDS per-wave -> no __syncthreads.
// All 21 weight B-fragments are hoisted into persistent VGPRs (no per-
// iteration ws reads); streaming k/q/pos/mask loads for iteration it+1 are
// issued mid-iteration so HBM latency hides under the MFMA+softmax work.
__global__ __launch_bounds__(256, 3) void attn2d_main(
    const float* __restrict__ q, const float* __restrict__ k,
    const float* __restrict__ pos,
    const float* __restrict__ pos_w1, const float* __restrict__ pos_b1,
    const float* __restrict__ attn_b2, const float* __restrict__ out_b,
    const int* __restrict__ mask,
    const float* __restrict__ ws, float* __restrict__ out)
{
    __shared__ float rh_lds[4][16 * 12];  // relu(hid) C->A transpose, per wave
    __shared__ float x_lds[4][8 * 68];    // x rows, per wave

    const int tid  = threadIdx.x;
    const int lane = tid & 63;
    const int wiv  = __builtin_amdgcn_readfirstlane(tid >> 6);
    const int q4   = lane >> 4;
    const int col  = lane & 15;

    float* rh_w = rh_lds[wiv];
    float* x_w  = x_lds[wiv];

    const int wid = blockIdx.x * 4 + wiv;       // 0..8191
    const bf16x8* img = (const bf16x8*)(ws + WS_IMG);

    // ---- persistent B-fragments: hoisted once, live across the whole loop ----
    bf16x8 Bh[4];
    #pragma unroll
    for (int c = 0; c < 4; ++c) Bh[c] = img[(IMG_BH + c) * 64 + lane];
    const bf16x8 Bct = img[IMG_BCT * 64 + lane];
    bf16x8 Bv[4][2], Bp[4], Bw[4];
    #pragma unroll
    for (int t = 0; t < 4; ++t) {
        Bv[t][0] = img[(IMG_BV + t * 2) * 64 + lane];
        Bv[t][1] = img[(IMG_BV + t * 2 + 1) * 64 + lane];
        Bp[t]    = img[(IMG_BP + t) * 64 + lane];
        Bw[t]    = img[(IMG_BW2 + t) * 64 + lane];
    }

    float spb[4], b2a[4];
    #pragma unroll
    for (int t = 0; t < 4; ++t) {
        spb[t] = ws[WS_SPB + t * 16 + col];     // (s + pos_b2) at d = t*16+col
        b2a[t] = attn_b2[t * 16 + col];
    }
    const float c0r = (col < 8) ? ws[WS_C0 + col] : 0.f;
    const int bnp = q4 >> 1;                    // which bn of the pair this lane's rows belong to

    // raw-load helper (addresses uniform-per-wave in PAIR, per-lane in col/q4)
#define LOADRAW(PAIR, RK, RQ, RP, RM) do {                                    \
        const size_t kb_ = ((size_t)(PAIR) * 16 + col) * 64 + q4 * 8;         \
        RK[0] = *(const float4*)(k + kb_);                                    \
        RK[1] = *(const float4*)(k + kb_ + 4);                                \
        RK[2] = *(const float4*)(k + kb_ + 32);                               \
        RK[3] = *(const float4*)(k + kb_ + 36);                               \
        const size_t qb_ = ((size_t)(PAIR) * 2 + (col >> 3)) * 64 + q4 * 8;   \
        RQ[0] = *(const float4*)(q + qb_);                                    \
        RQ[1] = *(const float4*)(q + qb_ + 4);                                \
        RQ[2] = *(const float4*)(q + qb_ + 32);                               \
        RQ[3] = *(const float4*)(q + qb_ + 36);                               \
        if (lane < 16)                                                        \
            RP = *(const float4*)(pos + ((size_t)(PAIR) * 16 + lane) * 4);    \
        RM = *(const int4*)(mask + (size_t)(PAIR) * 16 + q4 * 4);             \
    } while (0)

    float4 rk[4], rq[4], rp = make_float4(0.f, 0.f, 0.f, 0.f);
    int4   rm = make_int4(1, 1, 1, 1);
    LOADRAW(wid * 4, rk, rq, rp, rm);

    #pragma unroll
    for (int it = 0; it < 4; ++it) {
        const int pair = wid * 4 + it;          // uniform per wave

        // ---- pack current raws into MFMA A-fragments ----
        bf16x8 Ak[2], Aq[2];
        Ak[0] = pack2f4(rk[0], rk[1]);
        Ak[1] = pack2f4(rk[2], rk[3]);
        Aq[0] = pack2f4(rq[0], rq[1]);
        Aq[1] = pack2f4(rq[2], rq[3]);
        const int mm[4] = {rm.x, rm.y, rm.z, rm.w};

        // hp = relu(pos . pos_w1 + b1), rows on lanes 0-15 (A-fragment, k=g)
        bf16x8 Ahp{};
        if (lane < 16) {
            float hv[8];
            #pragma unroll
            for (int g = 0; g < 8; ++g)
                hv[g] = fmaxf(pos_b1[g] + rp.x * pos_w1[g] + rp.y * pos_w1[8 + g] +
                              rp.z * pos_w1[16 + g] + rp.w * pos_w1[24 + g], 0.f);
            Ahp = pack8(hv);
        }

        // ---- prefetch next iteration's raws; latency hides under the MFMAs ----
        float4 nk[4], nq[4], np = make_float4(0.f, 0.f, 0.f, 0.f);
        int4   nm = make_int4(1, 1, 1, 1);
        if (it < 3) LOADRAW(pair + 1, nk, nq, np, nm);

        // HID: hid[16x8] = k.At - q.Bqt + hp.Ct  (cols 0-7 valid)
        f32x4 acch = {0.f, 0.f, 0.f, 0.f};
        acch = __builtin_amdgcn_mfma_f32_16x16x32_bf16(Ak[0], Bh[0], acch, 0, 0, 0);
        acch = __builtin_amdgcn_mfma_f32_16x16x32_bf16(Ak[1], Bh[1], acch, 0, 0, 0);
        acch = __builtin_amdgcn_mfma_f32_16x16x32_bf16(Aq[0], Bh[2], acch, 0, 0, 0);
        acch = __builtin_amdgcn_mfma_f32_16x16x32_bf16(Aq[1], Bh[3], acch, 0, 0, 0);
        acch = __builtin_amdgcn_mfma_f32_16x16x32_bf16(Ahp,   Bct,   acch, 0, 0, 0);
        if (col < 8) {
            #pragma unroll
            for (int r = 0; r < 4; ++r)
                rh_w[(q4 * 4 + r) * 12 + col] = fmaxf(acch[r] + c0r, 0.f);
        }

        // rh C->A transpose (16 rows x 8 h), A rows on lanes 0-15, k=h
        bf16x8 Arh{};
        if (q4 == 0) {
            float4 a  = *(const float4*)&rh_w[col * 12];
            float4 bb = *(const float4*)&rh_w[col * 12 + 4];
            Arh = pack2f4(a, bb);
        }

        // per output-column tile t: vh+p and att in matching C layout,
        // masked softmax over the 8 views entirely in registers.
        #pragma unroll
        for (int t = 0; t < 4; ++t) {
            f32x4 vh = {0.f, 0.f, 0.f, 0.f};
            vh = __builtin_amdgcn_mfma_f32_16x16x32_bf16(Ak[0], Bv[t][0], vh, 0, 0, 0);
            vh = __builtin_amdgcn_mfma_f32_16x16x32_bf16(Ak[1], Bv[t][1], vh, 0, 0, 0);
            vh = __builtin_amdgcn_mfma_f32_16x16x32_bf16(Ahp,   Bp[t],    vh, 0, 0, 0);
            f32x4 at = {0.f, 0.f, 0.f, 0.f};
            at = __builtin_amdgcn_mfma_f32_16x16x32_bf16(Arh, Bw[t], at, 0, 0, 0);

            float lg[4];
            #pragma unroll
            for (int r = 0; r < 4; ++r)
                lg[r] = (mm[r] != 0) ? (at[r] + b2a[t]) : -1e9f;

            float mx = fmaxf(fmaxf(lg[0], lg[1]), fmaxf(lg[2], lg[3]));
            mx = fmaxf(mx, swz16(mx));
            float wsum = 0.f, xp = 0.f;
            #pragma unroll
            for (int r = 0; r < 4; ++r) {
                const float wv = __expf(lg[r] - mx);
                wsum += wv;
                xp   += wv * (vh[r] + spb[t]);
            }
            wsum += swz16(wsum);
            xp   += swz16(xp);
            const float xv = xp * __builtin_amdgcn_rcpf(wsum);
            if ((q4 & 1) == 0)
                x_w[(it * 2 + bnp) * 68 + t * 16 + col] = xv;
        }

        // rotate prefetch buffers (SSA after full unroll; no real copies)
        if (it < 3) {
            #pragma unroll
            for (int c = 0; c < 4; ++c) { rk[c] = nk[c]; rq[c] = nq[c]; }
            rp = np; rm = nm;
        }
    }
#undef LOADRAW

    // OUT: out[8 x 64] = x . out_w + out_b (rows 8-15 duplicate rows 0-7, discarded)
    bf16x8 Ax[2];
    #pragma unroll
    for (int c = 0; c < 2; ++c)
        Ax[c] = loadpack(&x_w[(col & 7) * 68 + c * 32 + q4 * 8]);
    bf16x8 Bo[4][2];
    #pragma unroll
    for (int t = 0; t < 4; ++t) {
        Bo[t][0] = img[(IMG_BO + t * 2) * 64 + lane];
        Bo[t][1] = img[(IMG_BO + t * 2 + 1) * 64 + lane];
    }
    #pragma unroll
    for (int t = 0; t < 4; ++t) {
        f32x4 a = {0.f, 0.f, 0.f, 0.f};
        a = __builtin_amdgcn_mfma_f32_16x16x32_bf16(Ax[0], Bo[t][0], a, 0, 0, 0);
        a = __builtin_amdgcn_mfma_f32_16x16x32_bf16(Ax[1], Bo[t][1], a, 0, 0, 0);
        const float ob = out_b[t * 16 + col];
        #pragma unroll
        for (int r = 0; r < 4; ++r) {
            const int row = q4 * 4 + r;
            if (row < 8)
                out[((size_t)wid * 8 + row) * 64 + t * 16 + col] = a[r] + ob;
        }
    }
}

extern "C" void kernel_launch(void* const* d_in, const int* in_sizes, int n_in,
                              void* d_out, int out_size, void* d_ws, size_t ws_size,
                              hipStream_t stream) {
    const float* q        = (const float*)d_in[0];
    const float* k        = (const float*)d_in[1];
    const float* pos      = (const float*)d_in[2];
    const float* strength = (const float*)d_in[3];
    const float* q_tbl    = (const float*)d_in[4];
    const float* k_tbl    = (const float*)d_in[5];
    const float* v_tbl    = (const float*)d_in[6];
    const float* pos_w1   = (const float*)d_in[7];
    const float* pos_b1   = (const float*)d_in[8];
    const float* pos_w2   = (const float*)d_in[9];
    const float* pos_b2   = (const float*)d_in[10];
    const float* attn_w1  = (const float*)d_in[11];
    const float* attn_b1  = (const float*)d_in[12];
    const float* attn_w2  = (const float*)d_in[13];
    const float* attn_b2  = (const float*)d_in[14];
    const float* out_w    = (const float*)d_in[15];
    const float* out_b    = (const float*)d_in[16];
    const float* str_w    = (const float*)d_in[17];
    const float* str_b    = (const float*)d_in[18];
    const int*   mask     = (const int*)d_in[19];
    const int*   embed    = (const int*)d_in[20];
    float* ws  = (float*)d_ws;
    float* out = (float*)d_out;

    hipLaunchKernelGGL(precompute_kernel, dim3(30), dim3(256), 0, stream,
                       strength, str_w, str_b, q_tbl, k_tbl, v_tbl, out_w,
                       attn_w1, attn_b1, attn_w2, pos_w2, pos_b2, embed, ws);
    hipLaunchKernelGGL(attn2d_main, dim3(2048), dim3(256), 0, stream,
                       q, k, pos, pos_w1, pos_b1, attn_b2, out_b, mask, ws, out);
}

// Round 4
// 266.500 us; speedup vs baseline: 1.0715x; 1.0715x over previous
//
#include <hip/hip_runtime.h>

#define TBL 4096

// ---- ws float-layout ----
#define WS_SPB 0      // 64 f32 : s[d] + pos_b2[d]
#define WS_C0  64     // 8 f32  : attn_b1[h] + sum_d pos_b2[d]*w1[d][h]
#define WS_IMG 128    // bf16 lane-images, 29 images x 64 lanes x 16B (256 f32 slots each)
// image indices
#define IMG_BH  0     // 4 chunks: 0,1 = At (k path); 2,3 = -Bqt (q path)
#define IMG_BCT 4     // 1
#define IMG_BP  5     // 4 (t): pos_w2 B-frag
#define IMG_BW2 9     // 4 (t): attn_w2 B-frag
#define IMG_BV  13    // 8 (t*2+c): Wv B-frag
#define IMG_BO  21    // 8 (t*2+c): out_w B-frag
#define N_IMG   29
// total ws = 128 + 29*256 = 7552 floats = 30208 bytes

typedef __attribute__((ext_vector_type(8))) short bf16x8;
typedef __attribute__((ext_vector_type(4))) float f32x4;

__device__ inline int cvt2bf(float a, float b) {
    int r;
    asm("v_cvt_pk_bf16_f32 %0, %1, %2" : "=v"(r) : "v"(a), "v"(b));
    return r;
}

__device__ inline bf16x8 pack8(const float* x) {
    union { int4 i; bf16x8 b; } u;
    u.i.x = cvt2bf(x[0], x[1]);
    u.i.y = cvt2bf(x[2], x[3]);
    u.i.z = cvt2bf(x[4], x[5]);
    u.i.w = cvt2bf(x[6], x[7]);
    return u.b;
}

__device__ inline bf16x8 pack2f4(float4 a, float4 b) {
    float t[8] = {a.x, a.y, a.z, a.w, b.x, b.y, b.z, b.w};
    return pack8(t);
}

__device__ inline bf16x8 loadpack(const float* p) {
    float4 a = *(const float4*)p;
    float4 b = *(const float4*)(p + 4);
    return pack2f4(a, b);
}

// lane <-> lane^16 exchange (q4 pair swap), BitMode xor=16
__device__ inline float swz16(float x) {
    return __int_as_float(__builtin_amdgcn_ds_swizzle(__float_as_int(x), 0x401F));
}

// Latency-optimized precompute: 30 blocks x 256 threads. Every reduction loop
// is fully unrolled with the d-dimension split across 4 thread-groups (LDS
// tree reduce) so cold HBM loads overlap instead of serializing.
// UNCHANGED from the round-2 kernel (best dur config) - one variable per experiment.
__global__ __launch_bounds__(256) void precompute_kernel(
    const float* __restrict__ strength, const float* __restrict__ str_w,
    const float* __restrict__ str_b,
    const float* __restrict__ q_tbl, const float* __restrict__ k_tbl,
    const float* __restrict__ v_tbl, const float* __restrict__ out_w,
    const float* __restrict__ attn_w1, const float* __restrict__ attn_b1,
    const float* __restrict__ attn_w2,
    const float* __restrict__ pos_w2, const float* __restrict__ pos_b2,
    const int* __restrict__ embed_id, float* __restrict__ ws)
{
    __shared__ float red[4][64];        // block 0: s partials
    __shared__ float red2[4][64][8];    // image blocks: 4-way d partials

    const int t    = threadIdx.x;
    const int b    = blockIdx.x;
    const int id   = embed_id[0];
    const int lane = t & 63;
    const int dp   = t >> 6;            // d-partition / thread-group 0..3
    const int q4   = lane >> 4;
    const int col  = lane & 15;

    if (b == 0) {
        // s[d] = strength . str_w[:,d] ; 4 partitions x 128 i, 4 accumulators.
        {
            const float* st = strength + dp * 128;
            const float* sw = str_w + (size_t)(dp * 128) * 64 + lane;
            float a0 = 0.f, a1 = 0.f, a2 = 0.f, a3 = 0.f;
            #pragma unroll
            for (int i = 0; i < 128; i += 4) {
                a0 += st[i]     * sw[(size_t)(i)     * 64];
                a1 += st[i + 1] * sw[(size_t)(i + 1) * 64];
                a2 += st[i + 2] * sw[(size_t)(i + 2) * 64];
                a3 += st[i + 3] * sw[(size_t)(i + 3) * 64];
            }
            red[dp][lane] = (a0 + a1) + (a2 + a3);
        }
        // C0[h] = attn_b1[h] + pos_b2 . attn_w1[:,h]  (fully unrolled, tiny)
        if (t < 8) {
            float c = attn_b1[t];
            #pragma unroll
            for (int d = 0; d < 64; ++d) c += pos_b2[d] * attn_w1[d * 8 + t];
            ws[WS_C0 + t] = c;
        }
        __syncthreads();
        if (t < 64)
            ws[WS_SPB + t] = red[0][t] + red[1][t] + red[2][t] + red[3][t]
                           + str_b[t] + pos_b2[t];
        return;
    }

    const int im = b - 1;               // 0..28

    if (im < 5) {
        // dot-product images: split the 64-term d-reduction across dp groups
        float val[8];
        #pragma unroll
        for (int j = 0; j < 8; ++j) val[j] = 0.f;

        if (im < 4) {                   // HID chunks: B[k][n=col<8]
            const float* tbl = (im < 2 ? k_tbl : q_tbl) + (size_t)id * TBL;
            const int kb = (im & 1) * 32 + q4 * 8;
            if (col < 8) {
                #pragma unroll
                for (int dd = 0; dd < 16; ++dd) {
                    const int d = dp * 16 + dd;
                    const float w = attn_w1[d * 8 + col];
                    const float4 t0 = *(const float4*)(tbl + d * 64 + kb);
                    const float4 t1 = *(const float4*)(tbl + d * 64 + kb + 4);
                    val[0] += t0.x * w; val[1] += t0.y * w;
                    val[2] += t0.z * w; val[3] += t0.w * w;
                    val[4] += t1.x * w; val[5] += t1.y * w;
                    val[6] += t1.z * w; val[7] += t1.w * w;
                }
            }
        } else {                        // Ct: B[k=g (q4==0)][n=col<8]
            if (q4 == 0 && col < 8) {
                #pragma unroll
                for (int dd = 0; dd < 16; ++dd) {
                    const int d = dp * 16 + dd;
                    const float w = attn_w1[d * 8 + col];
                    #pragma unroll
                    for (int j = 0; j < 8; ++j) val[j] += pos_w2[j * 64 + d] * w;
                }
            }
        }
        #pragma unroll
        for (int j = 0; j < 8; ++j) red2[dp][lane][j] = val[j];
        __syncthreads();
        if (dp == 0) {
            const float sgn = (im == 2 || im == 3) ? -1.f : 1.f;
            float v2[8];
            #pragma unroll
            for (int j = 0; j < 8; ++j)
                v2[j] = sgn * (red2[0][lane][j] + red2[1][lane][j] +
                               red2[2][lane][j] + red2[3][lane][j]);
            ((bf16x8*)(ws + WS_IMG))[im * 64 + lane] = pack8(v2);
        }
        return;
    }

    // copy/reformat images: one thread-group, fully unrolled loads
    if (dp == 0) {
        float val[8];
        #pragma unroll
        for (int j = 0; j < 8; ++j) val[j] = 0.f;

        if (im < 9) {                   // Bp[t]: B[k=g (q4==0)][n=d]
            const int tt = im - 5;
            if (q4 == 0) {
                #pragma unroll
                for (int j = 0; j < 8; ++j) val[j] = pos_w2[j * 64 + tt * 16 + col];
            }
        } else if (im < 13) {           // Bw2[t]: B[k=h (q4==0)][n=d]
            const int tt = im - 9;
            if (q4 == 0) {
                #pragma unroll
                for (int j = 0; j < 8; ++j) val[j] = attn_w2[j * 64 + tt * 16 + col];
            }
        } else if (im < 21) {           // Bv[t][c]: B[k=j][n=d] = Wv[n][k]
            const int e = im - 13, tt = e >> 1, c = e & 1;
            const float* p = v_tbl + (size_t)id * TBL +
                             (tt * 16 + col) * 64 + c * 32 + q4 * 8;
            const float4 t0 = *(const float4*)p;
            const float4 t1 = *(const float4*)(p + 4);
            val[0] = t0.x; val[1] = t0.y; val[2] = t0.z; val[3] = t0.w;
            val[4] = t1.x; val[5] = t1.y; val[6] = t1.z; val[7] = t1.w;
        } else {                        // Bo[t][c]: B[k=d][n=e] = out_w[d][e]
            const int e = im - 21, tt = e >> 1, c = e & 1;
            #pragma unroll
            for (int j = 0; j < 8; ++j)
                val[j] = out_w[(c * 32 + q4 * 8 + j) * 64 + tt * 16 + col];
        }
        ((bf16x8*)(ws + WS_IMG))[im * 64 + lane] = pack8(val);
    }
}

// One wave handles 8 bn (4 pairs of 2). rh/x LDS buffers are PER-WAVE.
// All 29 weight-fragment images are staged GLOBAL->LDS once per block
// (one __syncthreads); every in-loop fragment read is a ds_read_b128
// (~120cy, no L2 contention) instead of a vmem load (~600cy) - and unlike
// register-hoisting (round-3 failure: scratch spills) this costs no VGPRs.
__global__ __launch_bounds__(256, 4) void attn2d_main(
    const float* __restrict__ q, const float* __restrict__ k,
    const float* __restrict__ pos,
    const float* __restrict__ pos_w1, const float* __restrict__ pos_b1,
    const float* __restrict__ attn_b2, const float* __restrict__ out_b,
    const int* __restrict__ mask,
    const float* __restrict__ ws, float* __restrict__ out)
{
    __shared__ int4  img_lds[N_IMG * 64];   // 29 KB, shared by the block's 4 waves
    __shared__ float rh_lds[4][16 * 12];    // relu(hid) C->A transpose, per wave
    __shared__ float x_lds[4][8 * 68];      // x rows, per wave

    const int tid  = threadIdx.x;
    const int lane = tid & 63;
    const int wiv  = __builtin_amdgcn_readfirstlane(tid >> 6);
    const int q4   = lane >> 4;
    const int col  = lane & 15;

    // ---- stage fragment images into LDS (once per block) ----
    {
        const int4* src = (const int4*)(ws + WS_IMG);
        #pragma unroll
        for (int i = 0; i < 8; ++i) {
            const int idx = tid + i * 256;
            if (idx < N_IMG * 64) img_lds[idx] = src[idx];
        }
    }
    __syncthreads();

#define LDIMG(IDX) ({ union { int4 i; bf16x8 b; } u_; u_.i = img_lds[(IDX) * 64 + lane]; u_.b; })

    float* rh_w = rh_lds[wiv];
    float* x_w  = x_lds[wiv];

    const int wid = blockIdx.x * 4 + wiv;       // 0..8191

    // persistent HID B-fragments (read once per it-loop, keep in regs)
    bf16x8 Bh[4];
    #pragma unroll
    for (int c = 0; c < 4; ++c) Bh[c] = LDIMG(IMG_BH + c);
    const bf16x8 Bct = LDIMG(IMG_BCT);

    float spb[4], b2a[4];
    #pragma unroll
    for (int t = 0; t < 4; ++t) {
        spb[t] = ws[WS_SPB + t * 16 + col];     // (s + pos_b2) at d = t*16+col
        b2a[t] = attn_b2[t * 16 + col];
    }
    const float c0r = (col < 8) ? ws[WS_C0 + col] : 0.f;
    const int bnp = q4 >> 1;                    // which bn of the pair this lane's rows belong to

    #pragma unroll
    for (int it = 0; it < 4; ++it) {
        const int pair = wid * 4 + it;          // uniform per wave
        const int bn0  = pair * 2;

        // A fragments: k rows (16) and broadcast q rows
        bf16x8 Ak[2], Aq[2];
        #pragma unroll
        for (int c = 0; c < 2; ++c)
            Ak[c] = loadpack(k + ((size_t)pair * 16 + col) * 64 + c * 32 + q4 * 8);
        #pragma unroll
        for (int c = 0; c < 2; ++c)
            Aq[c] = loadpack(q + (size_t)(bn0 + (col >> 3)) * 64 + c * 32 + q4 * 8);

        // masks for this lane's 4 C-rows (tile row = q4*4+r)
        const int4 m4v = *(const int4*)(mask + (size_t)pair * 16 + q4 * 4);
        const int mm[4] = {m4v.x, m4v.y, m4v.z, m4v.w};

        // hp = relu(pos . pos_w1 + b1), rows on lanes 0-15 (A-fragment, k=g)
        bf16x8 Ahp{};
        if (lane < 16) {
            float4 pp = *(const float4*)(pos + ((size_t)pair * 16 + lane) * 4);
            float hv[8];
            #pragma unroll
            for (int g = 0; g < 8; ++g)
                hv[g] = fmaxf(pos_b1[g] + pp.x * pos_w1[g] + pp.y * pos_w1[8 + g] +
                              pp.z * pos_w1[16 + g] + pp.w * pos_w1[24 + g], 0.f);
            Ahp = pack8(hv);
        }

        // HID: hid[16x8] = k.At - q.Bqt + hp.Ct  (cols 0-7 valid)
        f32x4 acch = {0.f, 0.f, 0.f, 0.f};
        acch = __builtin_amdgcn_mfma_f32_16x16x32_bf16(Ak[0], Bh[0], acch, 0, 0, 0);
        acch = __builtin_amdgcn_mfma_f32_16x16x32_bf16(Ak[1], Bh[1], acch, 0, 0, 0);
        acch = __builtin_amdgcn_mfma_f32_16x16x32_bf16(Aq[0], Bh[2], acch, 0, 0, 0);
        acch = __builtin_amdgcn_mfma_f32_16x16x32_bf16(Aq[1], Bh[3], acch, 0, 0, 0);
        acch = __builtin_amdgcn_mfma_f32_16x16x32_bf16(Ahp,   Bct,   acch, 0, 0, 0);
        if (col < 8) {
            #pragma unroll
            for (int r = 0; r < 4; ++r)
                rh_w[(q4 * 4 + r) * 12 + col] = fmaxf(acch[r] + c0r, 0.f);
        }

        // rh C->A transpose (16 rows x 8 h), A rows on lanes 0-15, k=h
        bf16x8 Arh{};
        if (q4 == 0) {
            float4 a  = *(const float4*)&rh_w[col * 12];
            float4 bb = *(const float4*)&rh_w[col * 12 + 4];
            Arh = pack2f4(a, bb);
        }

        // per output-column tile t: vh+p and att in matching C layout,
        // masked softmax over the 8 views entirely in registers.
        #pragma unroll
        for (int t = 0; t < 4; ++t) {
            const bf16x8 Bv0 = LDIMG(IMG_BV + t * 2);
            const bf16x8 Bv1 = LDIMG(IMG_BV + t * 2 + 1);
            const bf16x8 Bp  = LDIMG(IMG_BP + t);
            const bf16x8 Bw  = LDIMG(IMG_BW2 + t);

            f32x4 vh = {0.f, 0.f, 0.f, 0.f};
            vh = __builtin_amdgcn_mfma_f32_16x16x32_bf16(Ak[0], Bv0, vh, 0, 0, 0);
            vh = __builtin_amdgcn_mfma_f32_16x16x32_bf16(Ak[1], Bv1, vh, 0, 0, 0);
            vh = __builtin_amdgcn_mfma_f32_16x16x32_bf16(Ahp,   Bp,  vh, 0, 0, 0);
            f32x4 at = {0.f, 0.f, 0.f, 0.f};
            at = __builtin_amdgcn_mfma_f32_16x16x32_bf16(Arh, Bw, at, 0, 0, 0);

            float lg[4];
            #pragma unroll
            for (int r = 0; r < 4; ++r)
                lg[r] = (mm[r] != 0) ? (at[r] + b2a[t]) : -1e9f;

            float mx = fmaxf(fmaxf(lg[0], lg[1]), fmaxf(lg[2], lg[3]));
            mx = fmaxf(mx, swz16(mx));
            float wsum = 0.f, xp = 0.f;
            #pragma unroll
            for (int r = 0; r < 4; ++r) {
                const float wv = __expf(lg[r] - mx);
                wsum += wv;
                xp   += wv * (vh[r] + spb[t]);
            }
            wsum += swz16(wsum);
            xp   += swz16(xp);
            const float xv = xp * __builtin_amdgcn_rcpf(wsum);
            if ((q4 & 1) == 0)
                x_w[(it * 2 + bnp) * 68 + t * 16 + col] = xv;
        }
    }

    // OUT: out[8 x 64] = x . out_w + out_b (rows 8-15 duplicate rows 0-7, discarded)
    bf16x8 Ax[2];
    #pragma unroll
    for (int c = 0; c < 2; ++c)
        Ax[c] = loadpack(&x_w[(col & 7) * 68 + c * 32 + q4 * 8]);
    #pragma unroll
    for (int t = 0; t < 4; ++t) {
        const bf16x8 Bo0 = LDIMG(IMG_BO + t * 2);
        const bf16x8 Bo1 = LDIMG(IMG_BO + t * 2 + 1);
        f32x4 a = {0.f, 0.f, 0.f, 0.f};
        a = __builtin_amdgcn_mfma_f32_16x16x32_bf16(Ax[0], Bo0, a, 0, 0, 0);
        a = __builtin_amdgcn_mfma_f32_16x16x32_bf16(Ax[1], Bo1, a, 0, 0, 0);
        const float ob = out_b[t * 16 + col];
        #pragma unroll
        for (int r = 0; r < 4; ++r) {
            const int row = q4 * 4 + r;
            if (row < 8)
                out[((size_t)wid * 8 + row) * 64 + t * 16 + col] = a[r] + ob;
        }
    }
#undef LDIMG
}

extern "C" void kernel_launch(void* const* d_in, const int* in_sizes, int n_in,
                              void* d_out, int out_size, void* d_ws, size_t ws_size,
                              hipStream_t stream) {
    const float* q        = (const float*)d_in[0];
    const float* k        = (const float*)d_in[1];
    const float* pos      = (const float*)d_in[2];
    const float* strength = (const float*)d_in[3];
    const float* q_tbl    = (const float*)d_in[4];
    const float* k_tbl    = (const float*)d_in[5];
    const float* v_tbl    = (const float*)d_in[6];
    const float* pos_w1   = (const float*)d_in[7];
    const float* pos_b1   = (const float*)d_in[8];
    const float* pos_w2   = (const float*)d_in[9];
    const float* pos_b2   = (const float*)d_in[10];
    const float* attn_w1  = (const float*)d_in[11];
    const float* attn_b1  = (const float*)d_in[12];
    const float* attn_w2  = (const float*)d_in[13];
    const float* attn_b2  = (const float*)d_in[14];
    const float* out_w    = (const float*)d_in[15];
    const float* out_b    = (const float*)d_in[16];
    const float* str_w    = (const float*)d_in[17];
    const float* str_b    = (const float*)d_in[18];
    const int*   mask     = (const int*)d_in[19];
    const int*   embed    = (const int*)d_in[20];
    float* ws  = (float*)d_ws;
    float* out = (float*)d_out;

    hipLaunchKernelGGL(precompute_kernel, dim3(30), dim3(256), 0, stream,
                       strength, str_w, str_b, q_tbl, k_tbl, v_tbl, out_w,
                       attn_w1, attn_b1, attn_w2, pos_w2, pos_b2, embed, ws);
    hipLaunchKernelGGL(attn2d_main, dim3(2048), dim3(256), 0, stream,
                       q, k, pos, pos_w1, pos_b1, attn_b2, out_b, mask, ws, out);
}

// Round 5
// 263.832 us; speedup vs baseline: 1.0823x; 1.0101x over previous
//
#include <hip/hip_runtime.h>

#define TBL 4096

// ---- ws float-layout ----
#define WS_SPB 0      // 64 f32 : s[d] + pos_b2[d]
#define WS_C0  64     // 8 f32  : attn_b1[h] + sum_d pos_b2[d]*w1[d][h]
#define WS_IMG 128    // bf16 lane-images, 29 images x 64 lanes x 16B (256 f32 slots each)
// image indices (in ws)
#define IMG_BH  0     // 4 chunks: 0,1 = At (k path); 2,3 = -Bqt (q path)
#define IMG_BCT 4     // 1
#define IMG_BP  5     // 4 (t): pos_w2 B-frag
#define IMG_BW2 9     // 4 (t): attn_w2 B-frag
#define IMG_BV  13    // 8 (t*2+c): Wv B-frag
#define IMG_BO  21    // 8 (t*2+c): out_w B-frag
#define N_IMG   29
// LDS stages only the 16 in-loop images, reordered: [Bv(8) | Bp(4) | Bw2(4)]
// lds idx li -> ws idx: li<8 ? 13+li : li-3

typedef __attribute__((ext_vector_type(8))) short bf16x8;
typedef __attribute__((ext_vector_type(4))) float f32x4;

__device__ inline int cvt2bf(float a, float b) {
    int r;
    asm("v_cvt_pk_bf16_f32 %0, %1, %2" : "=v"(r) : "v"(a), "v"(b));
    return r;
}

__device__ inline bf16x8 pack8(const float* x) {
    union { int4 i; bf16x8 b; } u;
    u.i.x = cvt2bf(x[0], x[1]);
    u.i.y = cvt2bf(x[2], x[3]);
    u.i.z = cvt2bf(x[4], x[5]);
    u.i.w = cvt2bf(x[6], x[7]);
    return u.b;
}

__device__ inline bf16x8 pack2f4(float4 a, float4 b) {
    float t[8] = {a.x, a.y, a.z, a.w, b.x, b.y, b.z, b.w};
    return pack8(t);
}

__device__ inline bf16x8 loadpack(const float* p) {
    float4 a = *(const float4*)p;
    float4 b = *(const float4*)(p + 4);
    return pack2f4(a, b);
}

__device__ inline unsigned short f2bf(float f) {
    union { float f; unsigned u; } v; v.f = f;
    unsigned r = v.u + 0x7fffu + ((v.u >> 16) & 1u);
    return (unsigned short)(r >> 16);
}

__device__ inline bf16x8 asbf(int4 v) {
    union { int4 i; bf16x8 b; } u; u.i = v; return u.b;
}

// lane <-> lane^16 exchange (q4 pair swap), BitMode xor=16
__device__ inline float swz16(float x) {
    return __int_as_float(__builtin_amdgcn_ds_swizzle(__float_as_int(x), 0x401F));
}

// Latency-optimized precompute: 30 blocks x 256 threads. UNCHANGED from the
// round-2/4 kernel - one variable per experiment.
__global__ __launch_bounds__(256) void precompute_kernel(
    const float* __restrict__ strength, const float* __restrict__ str_w,
    const float* __restrict__ str_b,
    const float* __restrict__ q_tbl, const float* __restrict__ k_tbl,
    const float* __restrict__ v_tbl, const float* __restrict__ out_w,
    const float* __restrict__ attn_w1, const float* __restrict__ attn_b1,
    const float* __restrict__ attn_w2,
    const float* __restrict__ pos_w2, const float* __restrict__ pos_b2,
    const int* __restrict__ embed_id, float* __restrict__ ws)
{
    __shared__ float red[4][64];        // block 0: s partials
    __shared__ float red2[4][64][8];    // image blocks: 4-way d partials

    const int t    = threadIdx.x;
    const int b    = blockIdx.x;
    const int id   = embed_id[0];
    const int lane = t & 63;
    const int dp   = t >> 6;            // d-partition / thread-group 0..3
    const int q4   = lane >> 4;
    const int col  = lane & 15;

    if (b == 0) {
        {
            const float* st = strength + dp * 128;
            const float* sw = str_w + (size_t)(dp * 128) * 64 + lane;
            float a0 = 0.f, a1 = 0.f, a2 = 0.f, a3 = 0.f;
            #pragma unroll
            for (int i = 0; i < 128; i += 4) {
                a0 += st[i]     * sw[(size_t)(i)     * 64];
                a1 += st[i + 1] * sw[(size_t)(i + 1) * 64];
                a2 += st[i + 2] * sw[(size_t)(i + 2) * 64];
                a3 += st[i + 3] * sw[(size_t)(i + 3) * 64];
            }
            red[dp][lane] = (a0 + a1) + (a2 + a3);
        }
        if (t < 8) {
            float c = attn_b1[t];
            #pragma unroll
            for (int d = 0; d < 64; ++d) c += pos_b2[d] * attn_w1[d * 8 + t];
            ws[WS_C0 + t] = c;
        }
        __syncthreads();
        if (t < 64)
            ws[WS_SPB + t] = red[0][t] + red[1][t] + red[2][t] + red[3][t]
                           + str_b[t] + pos_b2[t];
        return;
    }

    const int im = b - 1;               // 0..28

    if (im < 5) {
        float val[8];
        #pragma unroll
        for (int j = 0; j < 8; ++j) val[j] = 0.f;

        if (im < 4) {                   // HID chunks: B[k][n=col<8]
            const float* tbl = (im < 2 ? k_tbl : q_tbl) + (size_t)id * TBL;
            const int kb = (im & 1) * 32 + q4 * 8;
            if (col < 8) {
                #pragma unroll
                for (int dd = 0; dd < 16; ++dd) {
                    const int d = dp * 16 + dd;
                    const float w = attn_w1[d * 8 + col];
                    const float4 t0 = *(const float4*)(tbl + d * 64 + kb);
                    const float4 t1 = *(const float4*)(tbl + d * 64 + kb + 4);
                    val[0] += t0.x * w; val[1] += t0.y * w;
                    val[2] += t0.z * w; val[3] += t0.w * w;
                    val[4] += t1.x * w; val[5] += t1.y * w;
                    val[6] += t1.z * w; val[7] += t1.w * w;
                }
            }
        } else {                        // Ct: B[k=g (q4==0)][n=col<8]
            if (q4 == 0 && col < 8) {
                #pragma unroll
                for (int dd = 0; dd < 16; ++dd) {
                    const int d = dp * 16 + dd;
                    const float w = attn_w1[d * 8 + col];
                    #pragma unroll
                    for (int j = 0; j < 8; ++j) val[j] += pos_w2[j * 64 + d] * w;
                }
            }
        }
        #pragma unroll
        for (int j = 0; j < 8; ++j) red2[dp][lane][j] = val[j];
        __syncthreads();
        if (dp == 0) {
            const float sgn = (im == 2 || im == 3) ? -1.f : 1.f;
            float v2[8];
            #pragma unroll
            for (int j = 0; j < 8; ++j)
                v2[j] = sgn * (red2[0][lane][j] + red2[1][lane][j] +
                               red2[2][lane][j] + red2[3][lane][j]);
            ((bf16x8*)(ws + WS_IMG))[im * 64 + lane] = pack8(v2);
        }
        return;
    }

    if (dp == 0) {
        float val[8];
        #pragma unroll
        for (int j = 0; j < 8; ++j) val[j] = 0.f;

        if (im < 9) {                   // Bp[t]
            const int tt = im - 5;
            if (q4 == 0) {
                #pragma unroll
                for (int j = 0; j < 8; ++j) val[j] = pos_w2[j * 64 + tt * 16 + col];
            }
        } else if (im < 13) {           // Bw2[t]
            const int tt = im - 9;
            if (q4 == 0) {
                #pragma unroll
                for (int j = 0; j < 8; ++j) val[j] = attn_w2[j * 64 + tt * 16 + col];
            }
        } else if (im < 21) {           // Bv[t][c]
            const int e = im - 13, tt = e >> 1, c = e & 1;
            const float* p = v_tbl + (size_t)id * TBL +
                             (tt * 16 + col) * 64 + c * 32 + q4 * 8;
            const float4 t0 = *(const float4*)p;
            const float4 t1 = *(const float4*)(p + 4);
            val[0] = t0.x; val[1] = t0.y; val[2] = t0.z; val[3] = t0.w;
            val[4] = t1.x; val[5] = t1.y; val[6] = t1.z; val[7] = t1.w;
        } else {                        // Bo[t][c]
            const int e = im - 21, tt = e >> 1, c = e & 1;
            #pragma unroll
            for (int j = 0; j < 8; ++j)
                val[j] = out_w[(c * 32 + q4 * 8 + j) * 64 + tt * 16 + col];
        }
        ((bf16x8*)(ws + WS_IMG))[im * 64 + lane] = pack8(val);
    }
}

// One wave handles 8 bn (4 pairs of 2). LDS cut to ~23.5KB (16 in-loop images
// + rh + bf16 x) so LDS no longer caps occupancy; VGPR cap (256,4)=128 gives
// 16 waves/CU. Next-iteration k/q/pos/mask raws are prefetched in-register
// (viable now that B-fragments live in LDS, unlike round-3's spill).
__global__ __launch_bounds__(256, 4) void attn2d_main(
    const float* __restrict__ q, const float* __restrict__ k,
    const float* __restrict__ pos,
    const float* __restrict__ pos_w1, const float* __restrict__ pos_b1,
    const float* __restrict__ attn_b2, const float* __restrict__ out_b,
    const int* __restrict__ mask,
    const float* __restrict__ ws, float* __restrict__ out)
{
    __shared__ int4 img_lds[16 * 64];               // 16 KB: Bv(8), Bp(4), Bw2(4)
    __shared__ float rh_lds[4][16 * 12];            // 3 KB, per wave
    __shared__ unsigned short x_lds[4][8 * 72];     // 4.5 KB, bf16 x rows, per wave

    const int tid  = threadIdx.x;
    const int lane = tid & 63;
    const int wiv  = __builtin_amdgcn_readfirstlane(tid >> 6);
    const int q4   = lane >> 4;
    const int col  = lane & 15;

    const int4* gimg = (const int4*)(ws + WS_IMG);

    // ---- stage the 16 in-loop images into LDS (once per block) ----
    {
        #pragma unroll
        for (int i = 0; i < 4; ++i) {
            const int li = (tid >> 6) + i * 4;                  // 0..15
            const int wi = (li < 8) ? (13 + li) : (li - 3);     // ws image idx
            img_lds[li * 64 + lane] = gimg[wi * 64 + lane];
        }
    }
    __syncthreads();

#define LDIMG(IDX) asbf(img_lds[(IDX) * 64 + lane])

    float* rh_w = rh_lds[wiv];
    unsigned short* x_w = x_lds[wiv];

    const int wid = blockIdx.x * 4 + wiv;       // 0..8191

    // prologue-only fragments straight from global into registers
    bf16x8 Bh[4];
    #pragma unroll
    for (int c = 0; c < 4; ++c) Bh[c] = asbf(gimg[(IMG_BH + c) * 64 + lane]);
    const bf16x8 Bct = asbf(gimg[IMG_BCT * 64 + lane]);

    float spb[4], b2a[4];
    #pragma unroll
    for (int t = 0; t < 4; ++t) {
        spb[t] = ws[WS_SPB + t * 16 + col];     // (s + pos_b2) at d = t*16+col
        b2a[t] = attn_b2[t * 16 + col];
    }
    const float c0r = (col < 8) ? ws[WS_C0 + col] : 0.f;
    const int bnp = q4 >> 1;                    // which bn of the pair this lane's rows belong to

#define LOADRAW(PAIR, RK, RQ, RP, RM) do {                                    \
        const size_t kb_ = ((size_t)(PAIR) * 16 + col) * 64 + q4 * 8;         \
        RK[0] = *(const float4*)(k + kb_);                                    \
        RK[1] = *(const float4*)(k + kb_ + 4);                                \
        RK[2] = *(const float4*)(k + kb_ + 32);                               \
        RK[3] = *(const float4*)(k + kb_ + 36);                               \
        const size_t qb_ = ((size_t)(PAIR) * 2 + (col >> 3)) * 64 + q4 * 8;   \
        RQ[0] = *(const float4*)(q + qb_);                                    \
        RQ[1] = *(const float4*)(q + qb_ + 4);                                \
        RQ[2] = *(const float4*)(q + qb_ + 32);                               \
        RQ[3] = *(const float4*)(q + qb_ + 36);                               \
        if (lane < 16)                                                        \
            RP = *(const float4*)(pos + ((size_t)(PAIR) * 16 + lane) * 4);    \
        RM = *(const int4*)(mask + (size_t)(PAIR) * 16 + q4 * 4);             \
    } while (0)

    float4 rk[4], rq[4], rp = make_float4(0.f, 0.f, 0.f, 0.f);
    int4   rm = make_int4(1, 1, 1, 1);
    LOADRAW(wid * 4, rk, rq, rp, rm);

    #pragma unroll
    for (int it = 0; it < 4; ++it) {
        const int pair = wid * 4 + it;          // uniform per wave

        // ---- pack current raws into MFMA A-fragments ----
        bf16x8 Ak[2], Aq[2];
        Ak[0] = pack2f4(rk[0], rk[1]);
        Ak[1] = pack2f4(rk[2], rk[3]);
        Aq[0] = pack2f4(rq[0], rq[1]);
        Aq[1] = pack2f4(rq[2], rq[3]);
        const int mm[4] = {rm.x, rm.y, rm.z, rm.w};

        // hp = relu(pos . pos_w1 + b1), rows on lanes 0-15 (A-fragment, k=g)
        bf16x8 Ahp{};
        if (lane < 16) {
            float hv[8];
            #pragma unroll
            for (int g = 0; g < 8; ++g)
                hv[g] = fmaxf(pos_b1[g] + rp.x * pos_w1[g] + rp.y * pos_w1[8 + g] +
                              rp.z * pos_w1[16 + g] + rp.w * pos_w1[24 + g], 0.f);
            Ahp = pack8(hv);
        }

        // ---- prefetch next iteration's raws; latency hides under the MFMAs ----
        float4 nk[4], nq[4], np = make_float4(0.f, 0.f, 0.f, 0.f);
        int4   nm = make_int4(1, 1, 1, 1);
        if (it < 3) LOADRAW(pair + 1, nk, nq, np, nm);

        // HID: hid[16x8] = k.At - q.Bqt + hp.Ct  (cols 0-7 valid)
        f32x4 acch = {0.f, 0.f, 0.f, 0.f};
        acch = __builtin_amdgcn_mfma_f32_16x16x32_bf16(Ak[0], Bh[0], acch, 0, 0, 0);
        acch = __builtin_amdgcn_mfma_f32_16x16x32_bf16(Ak[1], Bh[1], acch, 0, 0, 0);
        acch = __builtin_amdgcn_mfma_f32_16x16x32_bf16(Aq[0], Bh[2], acch, 0, 0, 0);
        acch = __builtin_amdgcn_mfma_f32_16x16x32_bf16(Aq[1], Bh[3], acch, 0, 0, 0);
        acch = __builtin_amdgcn_mfma_f32_16x16x32_bf16(Ahp,   Bct,   acch, 0, 0, 0);
        if (col < 8) {
            #pragma unroll
            for (int r = 0; r < 4; ++r)
                rh_w[(q4 * 4 + r) * 12 + col] = fmaxf(acch[r] + c0r, 0.f);
        }

        // rh C->A transpose (16 rows x 8 h), A rows on lanes 0-15, k=h
        bf16x8 Arh{};
        if (q4 == 0) {
            float4 a  = *(const float4*)&rh_w[col * 12];
            float4 bb = *(const float4*)&rh_w[col * 12 + 4];
            Arh = pack2f4(a, bb);
        }

        // per output-column tile t: vh+p and att in matching C layout,
        // masked softmax over the 8 views entirely in registers.
        #pragma unroll
        for (int t = 0; t < 4; ++t) {
            const bf16x8 Bv0 = LDIMG(t * 2);
            const bf16x8 Bv1 = LDIMG(t * 2 + 1);
            const bf16x8 Bp  = LDIMG(8 + t);
            const bf16x8 Bw  = LDIMG(12 + t);

            f32x4 vh = {0.f, 0.f, 0.f, 0.f};
            vh = __builtin_amdgcn_mfma_f32_16x16x32_bf16(Ak[0], Bv0, vh, 0, 0, 0);
            vh = __builtin_amdgcn_mfma_f32_16x16x32_bf16(Ak[1], Bv1, vh, 0, 0, 0);
            vh = __builtin_amdgcn_mfma_f32_16x16x32_bf16(Ahp,   Bp,  vh, 0, 0, 0);
            f32x4 at = {0.f, 0.f, 0.f, 0.f};
            at = __builtin_amdgcn_mfma_f32_16x16x32_bf16(Arh, Bw, at, 0, 0, 0);

            float lg[4];
            #pragma unroll
            for (int r = 0; r < 4; ++r)
                lg[r] = (mm[r] != 0) ? (at[r] + b2a[t]) : -1e9f;

            float mx = fmaxf(fmaxf(lg[0], lg[1]), fmaxf(lg[2], lg[3]));
            mx = fmaxf(mx, swz16(mx));
            float wsum = 0.f, xp = 0.f;
            #pragma unroll
            for (int r = 0; r < 4; ++r) {
                const float wv = __expf(lg[r] - mx);
                wsum += wv;
                xp   += wv * (vh[r] + spb[t]);
            }
            wsum += swz16(wsum);
            xp   += swz16(xp);
            const float xv = xp * __builtin_amdgcn_rcpf(wsum);
            if ((q4 & 1) == 0)
                x_w[(it * 2 + bnp) * 72 + t * 16 + col] = f2bf(xv);
        }

        // rotate prefetch buffers (SSA after full unroll; no real copies)
        if (it < 3) {
            #pragma unroll
            for (int c = 0; c < 4; ++c) { rk[c] = nk[c]; rq[c] = nq[c]; }
            rp = np; rm = nm;
        }
    }
#undef LOADRAW

    // OUT: out[8 x 64] = x . out_w + out_b (x already bf16 in LDS)
    bf16x8 Bo[4][2];
    #pragma unroll
    for (int t = 0; t < 4; ++t) {
        Bo[t][0] = asbf(gimg[(IMG_BO + t * 2) * 64 + lane]);
        Bo[t][1] = asbf(gimg[(IMG_BO + t * 2 + 1) * 64 + lane]);
    }
    bf16x8 Ax[2];
    #pragma unroll
    for (int c = 0; c < 2; ++c)
        Ax[c] = *(const bf16x8*)&x_w[(col & 7) * 72 + c * 32 + q4 * 8];
    #pragma unroll
    for (int t = 0; t < 4; ++t) {
        f32x4 a = {0.f, 0.f, 0.f, 0.f};
        a = __builtin_amdgcn_mfma_f32_16x16x32_bf16(Ax[0], Bo[t][0], a, 0, 0, 0);
        a = __builtin_amdgcn_mfma_f32_16x16x32_bf16(Ax[1], Bo[t][1], a, 0, 0, 0);
        const float ob = out_b[t * 16 + col];
        #pragma unroll
        for (int r = 0; r < 4; ++r) {
            const int row = q4 * 4 + r;
            if (row < 8)
                out[((size_t)wid * 8 + row) * 64 + t * 16 + col] = a[r] + ob;
        }
    }
#undef LDIMG
}

extern "C" void kernel_launch(void* const* d_in, const int* in_sizes, int n_in,
                              void* d_out, int out_size, void* d_ws, size_t ws_size,
                              hipStream_t stream) {
    const float* q        = (const float*)d_in[0];
    const float* k        = (const float*)d_in[1];
    const float* pos      = (const float*)d_in[2];
    const float* strength = (const float*)d_in[3];
    const float* q_tbl    = (const float*)d_in[4];
    const float* k_tbl    = (const float*)d_in[5];
    const float* v_tbl    = (const float*)d_in[6];
    const float* pos_w1   = (const float*)d_in[7];
    const float* pos_b1   = (const float*)d_in[8];
    const float* pos_w2   = (const float*)d_in[9];
    const float* pos_b2   = (const float*)d_in[10];
    const float* attn_w1  = (const float*)d_in[11];
    const float* attn_b1  = (const float*)d_in[12];
    const float* attn_w2  = (const float*)d_in[13];
    const float* attn_b2  = (const float*)d_in[14];
    const float* out_w    = (const float*)d_in[15];
    const float* out_b    = (const float*)d_in[16];
    const float* str_w    = (const float*)d_in[17];
    const float* str_b    = (const float*)d_in[18];
    const int*   mask     = (const int*)d_in[19];
    const int*   embed    = (const int*)d_in[20];
    float* ws  = (float*)d_ws;
    float* out = (float*)d_out;

    hipLaunchKernelGGL(precompute_kernel, dim3(30), dim3(256), 0, stream,
                       strength, str_w, str_b, q_tbl, k_tbl, v_tbl, out_w,
                       attn_w1, attn_b1, attn_w2, pos_w2, pos_b2, embed, ws);
    hipLaunchKernelGGL(attn2d_main, dim3(2048), dim3(256), 0, stream,
                       q, k, pos, pos_w1, pos_b1, attn_b2, out_b, mask, ws, out);
}